// Round 1
// baseline (166.098 us; speedup 1.0000x reference)
//
#include <hip/hip_runtime.h>

// Problem constants (z: [32,64,32,32] fp32, codebook: [1024,64] fp32)
#define B_DIM   32
#define C_DIM   64
#define H_DIM   32
#define W_DIM   32
#define K_CODES 1024
#define HW      (H_DIM * W_DIM)          // 1024
#define CHW     (C_DIM * HW)             // 65536
#define N_TOTAL (B_DIM * HW)             // 32768
#define CODES_ELEMS (B_DIM * C_DIM * HW) // 2097152

#define KPARTS 8
#define NPB    64                        // n's per block
#define KP_LEN (K_CODES / KPARTS)        // 128

// numpy-style pairwise sum of squares over 64 elems:
// 8 accumulators stride-8, then ((r0+r1)+(r2+r3))+((r4+r5)+(r6+r7))
__device__ __forceinline__ float sumsq64_np(const float* v, int stride) {
    float r[8];
#pragma unroll
    for (int j = 0; j < 8; ++j) r[j] = v[j * stride] * v[j * stride];
#pragma unroll
    for (int i = 8; i < 64; i += 8) {
#pragma unroll
        for (int j = 0; j < 8; ++j) r[j] = fmaf(v[(i + j) * stride], v[(i + j) * stride], r[j]);
    }
    return ((r[0] + r[1]) + (r[2] + r[3])) + ((r[4] + r[5]) + (r[6] + r[7]));
}

__global__ void cnorm_kernel(const float* __restrict__ cb, float* __restrict__ cnorm) {
    int k = blockIdx.x * blockDim.x + threadIdx.x;
    if (k >= K_CODES) return;
    cnorm[k] = sumsq64_np(cb + k * C_DIM, 1);
}

__launch_bounds__(NPB * KPARTS)
__global__ void vq_kernel(const float* __restrict__ z, const float* __restrict__ cb,
                          const float* __restrict__ cnorm, float* __restrict__ out) {
    const int t    = threadIdx.x;
    const int nl   = t & (NPB - 1);      // local n within block (lane id)
    // wave index == k-partition; readfirstlane makes it provably wave-uniform
    // so codebook reads lower to s_load (scalar path, SGPR operand FMAs).
    const int part = __builtin_amdgcn_readfirstlane(t >> 6);

    const int n  = blockIdx.x * NPB + nl;
    const int b  = n >> 10;              // n / HW
    const int hw = n & (HW - 1);

    // Load this thread's x vector: z[b][c][h][w], coalesced across lanes per c.
    const float* zp = z + b * CHW + hw;
    float x[C_DIM];
#pragma unroll
    for (int c = 0; c < C_DIM; ++c) x[c] = zp[c * HW];

    // xnorm with numpy-pairwise order (mirrors jnp.sum(x*x, axis=1))
    float xr[8];
#pragma unroll
    for (int j = 0; j < 8; ++j) xr[j] = x[j] * x[j];
#pragma unroll
    for (int i = 8; i < 64; i += 8) {
#pragma unroll
        for (int j = 0; j < 8; ++j) xr[j] = fmaf(x[i + j], x[i + j], xr[j]);
    }
    const float xnorm = ((xr[0] + xr[1]) + (xr[2] + xr[3])) + ((xr[4] + xr[5]) + (xr[6] + xr[7]));

    // Scan this wave's k-partition. Ascending k + strict '<' = first-occurrence
    // argmin, matching np.argmin tie-break.
    float best = 3.4e38f;
    int   bidx = 0;
    const int k0 = part * KP_LEN;
    for (int k = k0; k < k0 + KP_LEN; ++k) {
        const float* cr = cb + k * C_DIM;   // wave-uniform address -> s_load
        float dot = 0.f;
#pragma unroll
        for (int c = 0; c < C_DIM; ++c) dot = fmaf(x[c], cr[c], dot);
        // Mirror reference expression order: (xnorm - 2*dot) + cnorm
        float dist = fmaf(-2.f, dot, xnorm) + cnorm[k];
        if (dist < best) { best = dist; bidx = k; }
    }

    // Cross-partition reduction in LDS (parts ordered ascending k; strict '<'
    // scanning p=0..7 keeps the lowest-k winner on exact ties).
    __shared__ float s_score[KPARTS][NPB];
    __shared__ int   s_idx[KPARTS][NPB];
    __shared__ int   s_best[NPB];
    s_score[part][nl] = best;
    s_idx[part][nl]   = bidx;
    __syncthreads();
    if (part == 0) {
        float bb = s_score[0][nl];
        int   bi = s_idx[0][nl];
#pragma unroll
        for (int p = 1; p < KPARTS; ++p) {
            float sc = s_score[p][nl];
            if (sc < bb) { bb = sc; bi = s_idx[p][nl]; }
        }
        s_best[nl] = bi;
        out[CODES_ELEMS + n] = (float)bi;   // indices output (as fp32)
    }
    __syncthreads();

    // Write codes: out[b][c][h][w] = codebook[idx][c]; each thread covers
    // c = part*8 .. part*8+7 for its n; coalesced across lanes per c.
    const int idx = s_best[nl];
    const float* sel = cb + idx * C_DIM;
    float* op = out + b * CHW + hw;
#pragma unroll
    for (int i = 0; i < 8; ++i) {
        const int c = part * 8 + i;
        op[c * HW] = sel[c];
    }
}

extern "C" void kernel_launch(void* const* d_in, const int* in_sizes, int n_in,
                              void* d_out, int out_size, void* d_ws, size_t ws_size,
                              hipStream_t stream) {
    const float* z  = (const float*)d_in[0];
    const float* cb = (const float*)d_in[1];
    float* out   = (float*)d_out;
    float* cnorm = (float*)d_ws;   // 1024 floats of scratch

    cnorm_kernel<<<(K_CODES + 255) / 256, 256, 0, stream>>>(cb, cnorm);
    vq_kernel<<<N_TOTAL / NPB, NPB * KPARTS, 0, stream>>>(z, cb, cnorm, out);
}

// Round 2
// 148.579 us; speedup vs baseline: 1.1179x; 1.1179x over previous
//
#include <hip/hip_runtime.h>

// z: [32,64,32,32] fp32, codebook: [1024,64] fp32
#define B_DIM   32
#define C_DIM   64
#define K_CODES 1024
#define HW      1024                     // 32*32
#define CHW     (C_DIM * HW)             // 65536
#define N_TOTAL (B_DIM * HW)             // 32768
#define CODES_ELEMS (B_DIM * C_DIM * HW) // 2097152

#define KPARTS 8
#define NPB    64                        // n's per block (lanes)
#define KP_LEN (K_CODES / KPARTS)        // 128
#define KGROUP 4                         // independent k-chains (ILP)

__launch_bounds__(NPB * KPARTS)
__global__ void vq_kernel(const float* __restrict__ z, const float* __restrict__ cb,
                          float* __restrict__ out) {
    const int t  = threadIdx.x;
    const int nl = t & (NPB - 1);
    // wave id == k partition; readfirstlane pins it wave-uniform so codebook
    // row reads lower to s_load (scalar path, SGPR-operand FMAs).
    const int part = __builtin_amdgcn_readfirstlane(t >> 6);

    // ---- Stage cnorm[0..1023] into LDS (2 rows per thread), numpy-pairwise
    // order to match jnp.sum(cb*cb, axis=1) rounding exactly.
    __shared__ float s_cnorm[K_CODES];
#pragma unroll
    for (int rep = 0; rep < 2; ++rep) {
        const int k = t + rep * 512;
        const float4* row = (const float4*)(cb + k * C_DIM);
        float v[C_DIM];
#pragma unroll
        for (int q = 0; q < 16; ++q) {
            float4 f = row[q];
            v[4*q+0] = f.x; v[4*q+1] = f.y; v[4*q+2] = f.z; v[4*q+3] = f.w;
        }
        float r[8];
#pragma unroll
        for (int j = 0; j < 8; ++j) r[j] = v[j] * v[j];
#pragma unroll
        for (int i = 8; i < 64; i += 8) {
#pragma unroll
            for (int j = 0; j < 8; ++j) r[j] = fmaf(v[i + j], v[i + j], r[j]);
        }
        s_cnorm[k] = ((r[0] + r[1]) + (r[2] + r[3])) + ((r[4] + r[5]) + (r[6] + r[7]));
    }

    // ---- Load this thread's x vector: z[b][c][h][w], coalesced across lanes.
    const int n  = blockIdx.x * NPB + nl;
    const int b  = n >> 10;
    const int hw = n & (HW - 1);
    const float* zp = z + b * CHW + hw;
    float x[C_DIM];
#pragma unroll
    for (int c = 0; c < C_DIM; ++c) x[c] = zp[c * HW];

    // xnorm, numpy-pairwise
    float xr[8];
#pragma unroll
    for (int j = 0; j < 8; ++j) xr[j] = x[j] * x[j];
#pragma unroll
    for (int i = 8; i < 64; i += 8) {
#pragma unroll
        for (int j = 0; j < 8; ++j) xr[j] = fmaf(x[i + j], x[i + j], xr[j]);
    }
    const float xnorm = ((xr[0] + xr[1]) + (xr[2] + xr[3])) + ((xr[4] + xr[5]) + (xr[6] + xr[7]));

    __syncthreads();   // s_cnorm ready

    // ---- Scan this wave's k partition, KGROUP independent dot chains.
    // Each dot's fp32 accumulation order is IDENTICAL to the serial version
    // (sequential over c) -> same rounding -> same argmin as round 1.
    float best = 3.4e38f;
    int   bidx = 0;
    const int k0 = part * KP_LEN;
    for (int kg = k0; kg < k0 + KP_LEN; kg += KGROUP) {
        const float* cr[KGROUP];
        float d[KGROUP];
#pragma unroll
        for (int j = 0; j < KGROUP; ++j) { cr[j] = cb + (kg + j) * C_DIM; d[j] = 0.f; }
#pragma unroll
        for (int c = 0; c < C_DIM; ++c) {
#pragma unroll
            for (int j = 0; j < KGROUP; ++j) d[j] = fmaf(x[c], cr[j][c], d[j]);
        }
#pragma unroll
        for (int j = 0; j < KGROUP; ++j) {
            // reference order: (xnorm - 2*dot) + cnorm
            float dist = fmaf(-2.f, d[j], xnorm) + s_cnorm[kg + j];
            if (dist < best) { best = dist; bidx = kg + j; }  // strict '<': first occurrence
        }
    }

    // ---- Cross-partition argmin reduce (ascending p, strict '<' keeps lowest k).
    __shared__ float s_score[KPARTS][NPB];
    __shared__ int   s_idx[KPARTS][NPB];
    __shared__ int   s_best[NPB];
    s_score[part][nl] = best;
    s_idx[part][nl]   = bidx;
    __syncthreads();
    if (part == 0) {
        float bb = s_score[0][nl];
        int   bi = s_idx[0][nl];
#pragma unroll
        for (int p = 1; p < KPARTS; ++p) {
            float sc = s_score[p][nl];
            if (sc < bb) { bb = sc; bi = s_idx[p][nl]; }
        }
        s_best[nl] = bi;
        out[CODES_ELEMS + n] = (float)bi;   // indices (fp32 in out buffer)
    }
    __syncthreads();

    // ---- Codes: out[b][c][h][w] = cb[idx][c]; 8 c's per partition, coalesced.
    const int idx = s_best[nl];
    const float* sel = cb + idx * C_DIM;
    float* op = out + b * CHW + hw;
#pragma unroll
    for (int i = 0; i < 8; ++i) {
        const int c = part * 8 + i;
        op[c * HW] = sel[c];
    }
}

extern "C" void kernel_launch(void* const* d_in, const int* in_sizes, int n_in,
                              void* d_out, int out_size, void* d_ws, size_t ws_size,
                              hipStream_t stream) {
    const float* z  = (const float*)d_in[0];
    const float* cb = (const float*)d_in[1];
    float* out = (float*)d_out;
    vq_kernel<<<N_TOTAL / NPB, NPB * KPARTS, 0, stream>>>(z, cb, out);
}